// Round 7
// baseline (256.364 us; speedup 1.0000x reference)
//
#include <hip/hip_runtime.h>
#include <stdint.h>

typedef __bf16 bf16;
typedef __bf16 bf16x2 __attribute__((ext_vector_type(2)));
typedef __bf16 bf16x4 __attribute__((ext_vector_type(4)));
typedef __bf16 bf16x8 __attribute__((ext_vector_type(8)));
typedef float f32x4 __attribute__((ext_vector_type(4)));
typedef float f32x2 __attribute__((ext_vector_type(2)));
typedef int i32x4 __attribute__((ext_vector_type(4)));
typedef unsigned u32x2 __attribute__((ext_vector_type(2)));
typedef unsigned u32x4 __attribute__((ext_vector_type(4)));

// XOR swizzle for [rows][32] bf16 LDS tiles (64B row stride).
__device__ __forceinline__ int swz(int row, int colb) {
    return (row * 64 + colb) ^ ((row & 7) << 4);
}

__device__ __forceinline__ unsigned packb(float a, float b) {
    bf16x2 t; t[0] = (bf16)a; t[1] = (bf16)b;
    return __builtin_bit_cast(unsigned, t);
}

// ---------------- mask -> bitmask (u32 per 32 keys) ----------------
__global__ __launch_bounds__(256) void mask_pack(
    const int* __restrict__ mask, unsigned long long* __restrict__ mbits)
{
    int lane = threadIdx.x & 63;
    int wid = (blockIdx.x * 256 + threadIdx.x) >> 6;
    int nw = (gridDim.x * 256) >> 6;
    const int niter = (4 * 1024 * 1024) / 64;
    for (int i = wid; i < niter; i += nw) {
        int v = mask[(size_t)i * 64 + lane];
        unsigned long long bb = __ballot(v != 0);
        if (lane == 0) mbits[i] = bb;
    }
}

// ---------------- weight transpose + f32->bf16 ----------------
__global__ __launch_bounds__(256) void wt_cvt(
    const float* __restrict__ w0, const float* __restrict__ w1,
    const float* __restrict__ w2, const float* __restrict__ w3,
    bf16* __restrict__ o0, bf16* __restrict__ o1,
    bf16* __restrict__ o2, bf16* __restrict__ o3)
{
    int z = blockIdx.z;
    const float* W = z == 0 ? w0 : z == 1 ? w1 : z == 2 ? w2 : w3;
    bf16* O = z == 0 ? o0 : z == 1 ? o1 : z == 2 ? o2 : o3;
    __shared__ float tile[32][33];
    int c0 = blockIdx.x * 32, r0 = blockIdx.y * 32;
    int tx = threadIdx.x, ty = threadIdx.y; // (32,8)
#pragma unroll
    for (int i = 0; i < 4; ++i)
        tile[ty + i * 8][tx] = W[(size_t)(r0 + ty + i * 8) * 1024 + c0 + tx];
    __syncthreads();
#pragma unroll
    for (int i = 0; i < 4; ++i)
        O[(size_t)(c0 + ty + i * 8) * 1024 + r0 + tx] = (bf16)tile[tx][ty + i * 8];
}

// ---------------- projection GEMM -> head-major bf16 ----------------
__global__ __launch_bounds__(256) void proj_gemm(
    const float* __restrict__ Aq, const float* __restrict__ Ak, const float* __restrict__ Av,
    const bf16* __restrict__ Wq, const bf16* __restrict__ Wk, const bf16* __restrict__ Wv,
    bf16* __restrict__ Oq, bf16* __restrict__ Ok, bf16* __restrict__ Ov)
{
    int z = blockIdx.z;
    const float* A = z == 0 ? Aq : z == 1 ? Ak : Av;
    const bf16* WT = z == 0 ? Wq : z == 1 ? Wk : Wv;
    bf16* O = z == 0 ? Oq : z == 1 ? Ok : Ov;

    __shared__ bf16 Al[128 * 32];
    __shared__ bf16 Bl[128 * 32];

    int tid = threadIdx.x;
    int w = tid >> 6, l = tid & 63;
    int l15 = l & 15, lg = l >> 4;
    int m0 = blockIdx.y * 128, n0 = blockIdx.x * 128;
    int wm = (w >> 1) * 64, wn = (w & 1) * 64;

    const f32x4 fz = {0.f, 0.f, 0.f, 0.f};
    f32x4 acc[4][4];
#pragma unroll
    for (int i = 0; i < 4; ++i)
#pragma unroll
        for (int j = 0; j < 4; ++j) acc[i][j] = fz;

    int ar = tid >> 1, ac = (tid & 1) * 16;

    for (int k0 = 0; k0 < 1024; k0 += 32) {
        const float* asrc = A + (size_t)(m0 + ar) * 1024 + k0 + ac;
        f32x4 f0 = *(const f32x4*)(asrc);
        f32x4 f1 = *(const f32x4*)(asrc + 4);
        f32x4 f2 = *(const f32x4*)(asrc + 8);
        f32x4 f3 = *(const f32x4*)(asrc + 12);
        bf16x8 b0, b1;
#pragma unroll
        for (int j = 0; j < 4; ++j) {
            b0[j] = (bf16)f0[j]; b0[4 + j] = (bf16)f1[j];
            b1[j] = (bf16)f2[j]; b1[4 + j] = (bf16)f3[j];
        }
        const bf16* bsrc = WT + (size_t)(n0 + ar) * 1024 + k0 + ac;
        bf16x8 bw0 = *(const bf16x8*)(bsrc);
        bf16x8 bw1 = *(const bf16x8*)(bsrc + 8);
        *(bf16x8*)((char*)Al + swz(ar, ac * 2))      = b0;
        *(bf16x8*)((char*)Al + swz(ar, ac * 2 + 16)) = b1;
        *(bf16x8*)((char*)Bl + swz(ar, ac * 2))      = bw0;
        *(bf16x8*)((char*)Bl + swz(ar, ac * 2 + 16)) = bw1;
        __syncthreads();
        bf16x8 af[4], bv[4];
#pragma unroll
        for (int i = 0; i < 4; ++i)
            af[i] = *(const bf16x8*)((const char*)Al + swz(wm + i * 16 + l15, lg * 16));
#pragma unroll
        for (int j = 0; j < 4; ++j)
            bv[j] = *(const bf16x8*)((const char*)Bl + swz(wn + j * 16 + l15, lg * 16));
#pragma unroll
        for (int i = 0; i < 4; ++i)
#pragma unroll
            for (int j = 0; j < 4; ++j)
                acc[i][j] = __builtin_amdgcn_mfma_f32_16x16x32_bf16(af[i], bv[j], acc[i][j], 0, 0, 0);
        __syncthreads();
    }
#pragma unroll
    for (int i = 0; i < 4; ++i)
#pragma unroll
        for (int j = 0; j < 4; ++j)
#pragma unroll
            for (int r = 0; r < 4; ++r) {
                int m = m0 + wm + i * 16 + lg * 4 + r;
                int n = n0 + wn + j * 16 + l15;
                int bb = m >> 10, s = m & 1023, h = n >> 6, d = n & 63;
                O[((size_t)(bb * 16 + h) * 1024 + s) * 64 + d] = (bf16)acc[i][j][r];
            }
}

// ---------------- Vh (B,H,S,64) -> VhT (B,H,64,S) ----------------
__global__ __launch_bounds__(512) void vh_t(const bf16* __restrict__ Vh, bf16* __restrict__ VhT)
{
    __shared__ bf16 tile[64][65];
    int bh = blockIdx.y;
    int s0 = blockIdx.x * 64;
    int tx = threadIdx.x, ty = threadIdx.y; // (64,8)
    const bf16* src = Vh + (size_t)bh * 1024 * 64;
#pragma unroll
    for (int i = 0; i < 8; ++i)
        tile[ty + i * 8][tx] = src[(size_t)(s0 + ty + i * 8) * 64 + tx];
    __syncthreads();
    bf16* dst = VhT + (size_t)bh * 64 * 1024;
#pragma unroll
    for (int i = 0; i < 8; ++i)
        dst[(size_t)(ty + i * 8) * 1024 + s0 + tx] = tile[tx][ty + i * 8];
}

// ---------------- kernel A: fused QK^T + masked exp + rowsum + PV ----------------
// grid (64 bh, 8 strips), block 512 (8 waves). Single-buffered K/V LDS with
// register prefetch (2 barriers/chunk); PV B-frags via wave-private St LDS
// round-trip (replaces 32 ds_bpermute/chunk with 8 b64 writes + 4 b128 reads).
__global__ __launch_bounds__(512, 4) void attn_pv(
    const bf16* __restrict__ Qh, const bf16* __restrict__ Kh,
    const bf16* __restrict__ VhT, const unsigned* __restrict__ mbits,
    float* __restrict__ rowinv, bf16* __restrict__ ctx)
{
    int bh = blockIdx.x;
    int b = bh >> 4, h = bh & 15;
    int tid = threadIdx.x;
    int w = tid >> 6, l = tid & 63;
    int l15 = l & 15, lg = l >> 4;
    int q0 = blockIdx.y * 128 + w * 16;

    const bf16* Qb = Qh + (size_t)bh * 65536;
    const bf16* Kb = Kh + (size_t)bh * 65536;
    const bf16* Vt = VhT + (size_t)bh * 65536;
    const unsigned* mbrow = mbits + ((size_t)b * 1024 + q0 + l15) * 32;

    __shared__ char lds[65536];
    char* const Kl = lds;                      // [128 keys][64 d] bf16 swz, 16KB
    char* const Vl = lds + 16384;              // [64 d][128 keys] bf16 swz, 16KB
    char* const St = lds + 32768 + w * 4096;   // wave-private [16 q][128 k] bf16

    const int skr = tid >> 2;            // key row 0..127
    const int skb = (tid & 3) * 32;      // byte in 128B row
    const int sks = (skr & 7) << 4;
    const int svr = tid >> 3;            // d row 0..63
    const int svb = (tid & 7) * 32;      // byte in 256B row
    const int svs = (svr & 7) << 4;
    const int rsw = (l15 & 7) << 4;
    const int ko0 = (lg * 16) ^ rsw;
    const int ko1 = (64 + lg * 16) ^ rsw;

    bf16x8 qf0 = *(const bf16x8*)(Qb + (size_t)(q0 + l15) * 64 + lg * 8);
    bf16x8 qf1 = *(const bf16x8*)(Qb + (size_t)(q0 + l15) * 64 + 32 + lg * 8);

    const f32x4 fz = {0.f, 0.f, 0.f, 0.f};

    {   // prologue: stage chunk 0 (K and V)
        const bf16* src = Kb + (size_t)skr * 64 + (skb >> 1);
        bf16x8 a = *(const bf16x8*)src;
        bf16x8 b2 = *(const bf16x8*)(src + 8);
        const bf16* vsrc = Vt + (size_t)svr * 1024 + (svb >> 1);
        bf16x8 va = *(const bf16x8*)vsrc;
        bf16x8 vb = *(const bf16x8*)(vsrc + 8);
        *(bf16x8*)(Kl + skr * 128 + (skb ^ sks)) = a;
        *(bf16x8*)(Kl + skr * 128 + ((skb + 16) ^ sks)) = b2;
        *(bf16x8*)(Vl + svr * 256 + (svb ^ svs)) = va;
        *(bf16x8*)(Vl + svr * 256 + ((svb + 16) ^ svs)) = vb;
    }
    __syncthreads();

    f32x4 oacc[4];
#pragma unroll
    for (int d0 = 0; d0 < 4; ++d0) oacc[d0] = fz;
    float ps = 0.f;

    for (int c = 0; c < 8; ++c) {
        bf16x8 nk0, nk1, nv0, nv1;
        if (c < 7) {   // prefetch chunk c+1 into registers (latency hidden by body)
            const bf16* src = Kb + (size_t)((c + 1) * 128 + skr) * 64 + (skb >> 1);
            nk0 = *(const bf16x8*)src;
            nk1 = *(const bf16x8*)(src + 8);
            const bf16* vsrc = Vt + (size_t)svr * 1024 + (c + 1) * 128 + (svb >> 1);
            nv0 = *(const bf16x8*)vsrc;
            nv1 = *(const bf16x8*)(vsrc + 8);
        }
        u32x4 mw = *(const u32x4*)(mbrow + c * 4);
        f32x4 st[8];
#pragma unroll
        for (int f = 0; f < 8; ++f) st[f] = fz;
#pragma unroll
        for (int f = 0; f < 8; ++f) {
            bf16x8 kf = *(const bf16x8*)(Kl + (f * 16 + l15) * 128 + ko0);
            st[f] = __builtin_amdgcn_mfma_f32_16x16x32_bf16(kf, qf0, st[f], 0, 0, 0);
        }
#pragma unroll
        for (int f = 0; f < 8; ++f) {
            bf16x8 kf = *(const bf16x8*)(Kl + (f * 16 + l15) * 128 + ko1);
            st[f] = __builtin_amdgcn_mfma_f32_16x16x32_bf16(kf, qf1, st[f], 0, 0, 0);
        }
        // masked exp; write P row-major into wave-private St (keys f*16+lg*4..+3)
#pragma unroll
        for (int f = 0; f < 8; ++f) {
            unsigned wb = mw[f >> 1] >> (((f & 1) << 4) + (lg << 2));
            f32x4 o;
            o[0] = (wb & 1u)        ? __expf(st[f][0] * 0.125f) : 0.f;
            o[1] = ((wb >> 1) & 1u) ? __expf(st[f][1] * 0.125f) : 0.f;
            o[2] = ((wb >> 2) & 1u) ? __expf(st[f][2] * 0.125f) : 0.f;
            o[3] = ((wb >> 3) & 1u) ? __expf(st[f][3] * 0.125f) : 0.f;
            ps += (o[0] + o[1]) + (o[2] + o[3]);
            u32x2 pr; pr[0] = packb(o[0], o[1]); pr[1] = packb(o[2], o[3]);
            *(u32x2*)(St + l15 * 256 + ((f * 32 + lg * 8) ^ rsw)) = pr;
        }
        // PV: B-frag = contiguous read of St row q=l15, keys ks*32+lg*8..+8
#pragma unroll
        for (int ks = 0; ks < 4; ++ks) {
            bf16x8 pf = *(const bf16x8*)(St + l15 * 256 + ((ks * 64 + lg * 16) ^ rsw));
#pragma unroll
            for (int d0 = 0; d0 < 4; ++d0) {
                bf16x8 vf = *(const bf16x8*)(Vl + (d0 * 16 + l15) * 256 + ((ks * 64 + lg * 16) ^ rsw));
                oacc[d0] = __builtin_amdgcn_mfma_f32_16x16x32_bf16(vf, pf, oacc[d0], 0, 0, 0);
            }
        }
        __syncthreads();   // all waves done reading Kl/Vl for chunk c
        if (c < 7) {
            *(bf16x8*)(Kl + skr * 128 + (skb ^ sks)) = nk0;
            *(bf16x8*)(Kl + skr * 128 + ((skb + 16) ^ sks)) = nk1;
            *(bf16x8*)(Vl + svr * 256 + (svb ^ svs)) = nv0;
            *(bf16x8*)(Vl + svr * 256 + ((svb + 16) ^ svs)) = nv1;
        }
        __syncthreads();   // chunk c+1 visible
    }
    // full row sum: merge the 4 lane-groups sharing q=l15
    ps += __shfl_xor(ps, 16, 64);
    ps += __shfl_xor(ps, 32, 64);
    float inv = 1.f / ps;
    if (l < 16) rowinv[(size_t)bh * 1024 + q0 + l15] = inv;

    bf16* crow = ctx + ((size_t)(b * 1024 + q0 + l15)) * 1024 + h * 64;
#pragma unroll
    for (int d0 = 0; d0 < 4; ++d0) {
        bf16x4 cv;
#pragma unroll
        for (int r = 0; r < 4; ++r) cv[r] = (bf16)(oacc[d0][r] * inv);
        *(bf16x4*)(crow + d0 * 16 + lg * 4) = cv;
    }
}

// ---------------- kernel B: attn writer (coalesced) ----------------
// St stride 288B: read conflicts 4-way (optimal), writes ~2-way. Mask via bitmask.
__global__ __launch_bounds__(512, 4) void attn_write(
    const bf16* __restrict__ Qh, const bf16* __restrict__ Kh,
    const unsigned* __restrict__ mbits, const float* __restrict__ rowinv,
    float* __restrict__ attn_out)
{
    int bh = blockIdx.x;
    int b = bh >> 4;
    int tid = threadIdx.x;
    int w = tid >> 6, l = tid & 63;
    int l15 = l & 15, lg = l >> 4;
    int q0 = blockIdx.y * 128 + w * 16;

    const bf16* Qb = Qh + (size_t)bh * 65536;
    const bf16* Kb = Kh + (size_t)bh * 65536;

    __shared__ char lds[69632];
    char* const K0 = lds;
    char* const K1 = lds + 16384;
    char* const St = lds + 32768 + w * 4608;   // 16 rows x 288B, wave-private

    const int skr = tid >> 2;
    const int skb = (tid & 3) * 32;
    const int sks = (skr & 7) << 4;
    const int rsw = (l15 & 7) << 4;
    const int ko0 = (lg * 16) ^ rsw;
    const int ko1 = (64 + lg * 16) ^ rsw;

    bf16x8 qf0 = *(const bf16x8*)(Qb + (size_t)(q0 + l15) * 64 + lg * 8);
    bf16x8 qf1 = *(const bf16x8*)(Qb + (size_t)(q0 + l15) * 64 + 32 + lg * 8);

    // readout lane coords: 8 lanes per q-row -> 128B segments
    const int rq = l >> 3;               // 0..7
    const int rk = (l & 7) * 4;          // 0..28
    const float iv0 = rowinv[(size_t)bh * 1024 + q0 + rq];
    const float iv1 = rowinv[(size_t)bh * 1024 + q0 + 8 + rq];
    const unsigned* mb0 = mbits + ((size_t)b * 1024 + q0 + rq) * 32;
    const unsigned* mb1 = mbits + ((size_t)b * 1024 + q0 + 8 + rq) * 32;
    float* abase = attn_out + ((size_t)bh * 1024 + q0) * 1024;

    const f32x4 fz = {0.f, 0.f, 0.f, 0.f};

    {   // stage chunk 0 K
        const bf16* src = Kb + (size_t)skr * 64 + (skb >> 1);
        bf16x8 a = *(const bf16x8*)src;
        bf16x8 bb2 = *(const bf16x8*)(src + 8);
        *(bf16x8*)(K0 + skr * 128 + (skb ^ sks)) = a;
        *(bf16x8*)(K0 + skr * 128 + ((skb + 16) ^ sks)) = bb2;
    }

    for (int c = 0; c < 8; ++c) {
        __syncthreads();
        bf16x8 nk0, nk1;
        if (c < 7) {
            const bf16* src = Kb + (size_t)((c + 1) * 128 + skr) * 64 + (skb >> 1);
            nk0 = *(const bf16x8*)src;
            nk1 = *(const bf16x8*)(src + 8);
        }
        u32x4 mw0 = *(const u32x4*)(mb0 + c * 4);
        u32x4 mw1 = *(const u32x4*)(mb1 + c * 4);
        const char* Kc = (c & 1) ? K1 : K0;
        f32x4 st[8];
#pragma unroll
        for (int f = 0; f < 8; ++f) st[f] = fz;
#pragma unroll
        for (int f = 0; f < 8; ++f) {
            bf16x8 kf = *(const bf16x8*)(Kc + (f * 16 + l15) * 128 + ko0);
            st[f] = __builtin_amdgcn_mfma_f32_16x16x32_bf16(kf, qf0, st[f], 0, 0, 0);
        }
#pragma unroll
        for (int f = 0; f < 8; ++f) {
            bf16x8 kf = *(const bf16x8*)(Kc + (f * 16 + l15) * 128 + ko1);
            st[f] = __builtin_amdgcn_mfma_f32_16x16x32_bf16(kf, qf1, st[f], 0, 0, 0);
        }
        // store exp(s) bf16 pairs to wave-private Stile (swizzled by q)
        const int qsw = (l15 & 7) << 3;
#pragma unroll
        for (int f = 0; f < 8; ++f) {
#pragma unroll
            for (int j = 0; j < 2; ++j) {
                unsigned val = packb(__expf(st[f][2 * j] * 0.125f),
                                     __expf(st[f][2 * j + 1] * 0.125f));
                int kbyte = f * 32 + lg * 8 + j * 4;
                *(unsigned*)(St + l15 * 288 + (kbyte ^ qsw)) = val;
            }
        }
        // readout: 8 rounds, coalesced attn store, bitmask
#pragma unroll
        for (int ri = 0; ri < 8; ++ri) {
            int qq = rq + 8 * (ri & 1);
            int kk = rk + 32 * (ri >> 1);
            bf16x4 pv4 = *(const bf16x4*)(St + qq * 288 + ((kk * 2) ^ ((qq & 7) << 3)));
            unsigned wm = ((ri & 1) ? mw1[ri >> 1] : mw0[ri >> 1]) >> rk;
            float iv = (ri & 1) ? iv1 : iv0;
            f32x4 o;
            o[0] = (wm & 1u)        ? (float)pv4[0] * iv : 0.f;
            o[1] = ((wm >> 1) & 1u) ? (float)pv4[1] * iv : 0.f;
            o[2] = ((wm >> 2) & 1u) ? (float)pv4[2] * iv : 0.f;
            o[3] = ((wm >> 3) & 1u) ? (float)pv4[3] * iv : 0.f;
            *(f32x4*)(abase + (size_t)qq * 1024 + c * 128 + kk) = o;
        }
        if (c < 7) {
            char* kdst = ((c & 1) ? K0 : K1) + skr * 128;
            *(bf16x8*)(kdst + (skb ^ sks)) = nk0;
            *(bf16x8*)(kdst + ((skb + 16) ^ sks)) = nk1;
        }
    }
}

// ---------------- FC GEMM + residual -> preLN f32 ----------------
__global__ __launch_bounds__(256) void fc_gemm(
    const bf16* __restrict__ ctx, const bf16* __restrict__ WT,
    const float* __restrict__ resid, float* __restrict__ preLN)
{
    __shared__ bf16 Al[128 * 32];
    __shared__ bf16 Bl[128 * 32];
    int tid = threadIdx.x;
    int w = tid >> 6, l = tid & 63;
    int l15 = l & 15, lg = l >> 4;
    int m0 = blockIdx.y * 128, n0 = blockIdx.x * 128;
    int wm = (w >> 1) * 64, wn = (w & 1) * 64;

    const f32x4 fz = {0.f, 0.f, 0.f, 0.f};
    f32x4 acc[4][4];
#pragma unroll
    for (int i = 0; i < 4; ++i)
#pragma unroll
        for (int j = 0; j < 4; ++j) acc[i][j] = fz;

    int ar = tid >> 1, ac = (tid & 1) * 16;

    for (int k0 = 0; k0 < 1024; k0 += 32) {
        const bf16* asrc = ctx + (size_t)(m0 + ar) * 1024 + k0 + ac;
        bf16x8 a0 = *(const bf16x8*)(asrc);
        bf16x8 a1 = *(const bf16x8*)(asrc + 8);
        const bf16* bsrc = WT + (size_t)(n0 + ar) * 1024 + k0 + ac;
        bf16x8 bw0 = *(const bf16x8*)(bsrc);
        bf16x8 bw1 = *(const bf16x8*)(bsrc + 8);
        *(bf16x8*)((char*)Al + swz(ar, ac * 2))      = a0;
        *(bf16x8*)((char*)Al + swz(ar, ac * 2 + 16)) = a1;
        *(bf16x8*)((char*)Bl + swz(ar, ac * 2))      = bw0;
        *(bf16x8*)((char*)Bl + swz(ar, ac * 2 + 16)) = bw1;
        __syncthreads();
        bf16x8 af[4], bv[4];
#pragma unroll
        for (int i = 0; i < 4; ++i)
            af[i] = *(const bf16x8*)((const char*)Al + swz(wm + i * 16 + l15, lg * 16));
#pragma unroll
        for (int j = 0; j < 4; ++j)
            bv[j] = *(const bf16x8*)((const char*)Bl + swz(wn + j * 16 + l15, lg * 16));
#pragma unroll
        for (int i = 0; i < 4; ++i)
#pragma unroll
            for (int j = 0; j < 4; ++j)
                acc[i][j] = __builtin_amdgcn_mfma_f32_16x16x32_bf16(af[i], bv[j], acc[i][j], 0, 0, 0);
        __syncthreads();
    }
#pragma unroll
    for (int i = 0; i < 4; ++i)
#pragma unroll
        for (int j = 0; j < 4; ++j)
#pragma unroll
            for (int r = 0; r < 4; ++r) {
                int m = m0 + wm + i * 16 + lg * 4 + r;
                int n = n0 + wn + j * 16 + l15;
                preLN[(size_t)m * 1024 + n] = acc[i][j][r] + resid[(size_t)m * 1024 + n];
            }
}

// ---------------- LayerNorm ----------------
__global__ __launch_bounds__(256) void ln_kernel(
    const float* __restrict__ x, const float* __restrict__ gamma,
    const float* __restrict__ beta, float* __restrict__ out)
{
    int row = blockIdx.x, t = threadIdx.x;
    const float* xr = x + (size_t)row * 1024;
    f32x4 v = *(const f32x4*)(xr + t * 4);
    float s = v[0] + v[1] + v[2] + v[3];
    float s2 = v[0] * v[0] + v[1] * v[1] + v[2] * v[2] + v[3] * v[3];
#pragma unroll
    for (int m = 1; m < 64; m <<= 1) {
        s += __shfl_xor(s, m, 64);
        s2 += __shfl_xor(s2, m, 64);
    }
    __shared__ float rs[4], rs2[4];
    if ((t & 63) == 0) { rs[t >> 6] = s; rs2[t >> 6] = s2; }
    __syncthreads();
    float S = rs[0] + rs[1] + rs[2] + rs[3];
    float S2 = rs2[0] + rs2[1] + rs2[2] + rs2[3];
    float mu = S * (1.f / 1024.f);
    float var = S2 * (1.f / 1024.f) - mu * mu;
    float rinv = rsqrtf(var + 1e-6f);
    f32x4 g = *(const f32x4*)(gamma + t * 4);
    f32x4 bb = *(const f32x4*)(beta + t * 4);
    f32x4 o;
#pragma unroll
    for (int j = 0; j < 4; ++j) o[j] = (v[j] - mu) * rinv * g[j] + bb[j];
    *(f32x4*)(out + (size_t)row * 1024 + t * 4) = o;
}

extern "C" void kernel_launch(void* const* d_in, const int* in_sizes, int n_in,
                              void* d_out, int out_size, void* d_ws, size_t ws_size,
                              hipStream_t stream) {
    const float* q     = (const float*)d_in[0];
    const float* k     = (const float*)d_in[1];
    const float* v     = (const float*)d_in[2];
    const int*   mask  = (const int*)d_in[3];
    const float* w_qs  = (const float*)d_in[4];
    const float* w_ks  = (const float*)d_in[5];
    const float* w_vs  = (const float*)d_in[6];
    const float* w_fc  = (const float*)d_in[7];
    const float* gamma = (const float*)d_in[8];
    const float* beta  = (const float*)d_in[9];

    float* out  = (float*)d_out;
    float* attn = out + (size_t)4 * 1024 * 1024; // second tuple output

    char* ws = (char*)d_ws;
    bf16* wqT   = (bf16*)(ws + (0ull  << 20));
    bf16* wkT   = (bf16*)(ws + (2ull  << 20));
    bf16* wvT   = (bf16*)(ws + (4ull  << 20));
    bf16* wfcT  = (bf16*)(ws + (6ull  << 20));
    bf16* Qh    = (bf16*)(ws + (8ull  << 20));
    bf16* Kh    = (bf16*)(ws + (16ull << 20));
    bf16* Vh    = (bf16*)(ws + (24ull << 20));
    bf16* VhT   = (bf16*)(ws + (32ull << 20));
    bf16* ctx   = (bf16*)(ws + (40ull << 20));
    float* preLN = (float*)(ws + (48ull << 20));
    // rowinv + mbits live in the Vh region (dead after vh_t)
    float* rowinv = (float*)(ws + (24ull << 20));
    unsigned long long* mbits = (unsigned long long*)(ws + (25ull << 20)); // 512KB

    wt_cvt<<<dim3(32, 32, 4), dim3(32, 8), 0, stream>>>(w_qs, w_ks, w_vs, w_fc,
                                                        wqT, wkT, wvT, wfcT);
    proj_gemm<<<dim3(8, 32, 3), 256, 0, stream>>>(q, k, v, wqT, wkT, wvT, Qh, Kh, Vh);
    vh_t<<<dim3(16, 64), dim3(64, 8), 0, stream>>>(Vh, VhT);
    mask_pack<<<256, 256, 0, stream>>>(mask, mbits);
    attn_pv<<<dim3(64, 8), 512, 0, stream>>>(Qh, Kh, VhT, (const unsigned*)mbits,
                                             rowinv, ctx);
    attn_write<<<dim3(64, 8), 512, 0, stream>>>(Qh, Kh, (const unsigned*)mbits,
                                                rowinv, attn);
    fc_gemm<<<dim3(8, 32), 256, 0, stream>>>(ctx, wfcT, q, preLN);
    ln_kernel<<<4096, 256, 0, stream>>>(preLN, gamma, beta, out);
}

// Round 8
// 235.670 us; speedup vs baseline: 1.0878x; 1.0878x over previous
//
#include <hip/hip_runtime.h>
#include <stdint.h>

typedef __bf16 bf16;
typedef __bf16 bf16x2 __attribute__((ext_vector_type(2)));
typedef __bf16 bf16x4 __attribute__((ext_vector_type(4)));
typedef __bf16 bf16x8 __attribute__((ext_vector_type(8)));
typedef float f32x4 __attribute__((ext_vector_type(4)));
typedef float f32x2 __attribute__((ext_vector_type(2)));
typedef int i32x4 __attribute__((ext_vector_type(4)));
typedef unsigned u32x2 __attribute__((ext_vector_type(2)));
typedef unsigned u32x4 __attribute__((ext_vector_type(4)));

// XOR swizzle for [rows][32] bf16 LDS tiles (64B row stride).
__device__ __forceinline__ int swz(int row, int colb) {
    return (row * 64 + colb) ^ ((row & 7) << 4);
}

__device__ __forceinline__ unsigned packb(float a, float b) {
    bf16x2 t; t[0] = (bf16)a; t[1] = (bf16)b;
    return __builtin_bit_cast(unsigned, t);
}

// async global->LDS 16B copy (dest = wave-uniform base + lane*16)
__device__ __forceinline__ void gload16(void* lds, const void* g) {
    __builtin_amdgcn_global_load_lds(
        (const __attribute__((address_space(1))) void*)g,
        (__attribute__((address_space(3))) void*)lds, 16, 0, 0);
}

// ---------------- q/k/v f32 -> bf16 ----------------
__global__ __launch_bounds__(256) void cvt_bf16(
    const float* __restrict__ q, const float* __restrict__ k, const float* __restrict__ v,
    bf16* __restrict__ oq, bf16* __restrict__ ok, bf16* __restrict__ ov)
{
    int z = blockIdx.z;
    const float* src = z == 0 ? q : z == 1 ? k : v;
    bf16* dst = z == 0 ? oq : z == 1 ? ok : ov;
    size_t i = ((size_t)blockIdx.x * 256 + threadIdx.x) * 8;
    f32x4 a = *(const f32x4*)(src + i);
    f32x4 b = *(const f32x4*)(src + i + 4);
    bf16x8 o;
#pragma unroll
    for (int j = 0; j < 4; ++j) { o[j] = (bf16)a[j]; o[4 + j] = (bf16)b[j]; }
    *(bf16x8*)(dst + i) = o;
}

// ---------------- mask -> bitmask (u32 per 32 keys) ----------------
__global__ __launch_bounds__(256) void mask_pack(
    const int* __restrict__ mask, unsigned long long* __restrict__ mbits)
{
    int lane = threadIdx.x & 63;
    int wid = (blockIdx.x * 256 + threadIdx.x) >> 6;
    int nw = (gridDim.x * 256) >> 6;
    const int niter = (4 * 1024 * 1024) / 64;
    for (int i = wid; i < niter; i += nw) {
        int v = mask[(size_t)i * 64 + lane];
        unsigned long long bb = __ballot(v != 0);
        if (lane == 0) mbits[i] = bb;
    }
}

// ---------------- weight transpose + f32->bf16 ----------------
__global__ __launch_bounds__(256) void wt_cvt(
    const float* __restrict__ w0, const float* __restrict__ w1,
    const float* __restrict__ w2, const float* __restrict__ w3,
    bf16* __restrict__ o0, bf16* __restrict__ o1,
    bf16* __restrict__ o2, bf16* __restrict__ o3)
{
    int z = blockIdx.z;
    const float* W = z == 0 ? w0 : z == 1 ? w1 : z == 2 ? w2 : w3;
    bf16* O = z == 0 ? o0 : z == 1 ? o1 : z == 2 ? o2 : o3;
    __shared__ float tile[32][33];
    int c0 = blockIdx.x * 32, r0 = blockIdx.y * 32;
    int tx = threadIdx.x, ty = threadIdx.y; // (32,8)
#pragma unroll
    for (int i = 0; i < 4; ++i)
        tile[ty + i * 8][tx] = W[(size_t)(r0 + ty + i * 8) * 1024 + c0 + tx];
    __syncthreads();
#pragma unroll
    for (int i = 0; i < 4; ++i)
        O[(size_t)(c0 + ty + i * 8) * 1024 + r0 + tx] = (bf16)tile[tx][ty + i * 8];
}

// ---------------- GEMM core (m97-style): global_load_lds staging ----------------
// A [.][1024] bf16 row-major, B=WT [.][1024] bf16 row-major (B^T form).
// 128x128 tile, BK=32, 256 threads. LDS content at swz() positions via
// inverse-swizzled per-lane global sources (linear LDS dest, rule #21).
// Inverse of swz for 16B chunk c: rr=c>>2; row=rr^((rr>>2)&1); cb=((c&3)*16)^((row&3)<<4).

// ---------------- projection GEMM -> head-major bf16 ----------------
__global__ __launch_bounds__(256) void proj_gemm(
    const bf16* __restrict__ Aq, const bf16* __restrict__ Ak, const bf16* __restrict__ Av,
    const bf16* __restrict__ Wq, const bf16* __restrict__ Wk, const bf16* __restrict__ Wv,
    bf16* __restrict__ Oq, bf16* __restrict__ Ok, bf16* __restrict__ Ov)
{
    int z = blockIdx.z;
    const bf16* A = z == 0 ? Aq : z == 1 ? Ak : Av;
    const bf16* WT = z == 0 ? Wq : z == 1 ? Wk : Wv;
    bf16* O = z == 0 ? Oq : z == 1 ? Ok : Ov;

    __shared__ bf16 Al[128 * 32];
    __shared__ bf16 Bl[128 * 32];

    int tid = threadIdx.x;
    int w = tid >> 6, l = tid & 63;
    int l15 = l & 15, lg = l >> 4;
    int m0 = blockIdx.y * 128, n0 = blockIdx.x * 128;
    int wm = (w >> 1) * 64, wn = (w & 1) * 64;

    // inverse-swizzle source coords for chunk c = tid (issue 0) / tid+256 (issue 1)
    int rr0 = tid >> 2;
    int row0 = rr0 ^ ((rr0 >> 2) & 1);
    int cbe = (((tid & 3) * 16) ^ ((row0 & 3) << 4)) >> 1;  // bf16 elems
    char* aldst0 = (char*)Al + w * 1024;
    char* aldst1 = (char*)Al + 4096 + w * 1024;
    char* bldst0 = (char*)Bl + w * 1024;
    char* bldst1 = (char*)Bl + 4096 + w * 1024;
    const bf16* asrc0 = A + (size_t)(m0 + row0) * 1024 + cbe;
    const bf16* asrc1 = A + (size_t)(m0 + row0 + 64) * 1024 + cbe;
    const bf16* bsrc0 = WT + (size_t)(n0 + row0) * 1024 + cbe;
    const bf16* bsrc1 = WT + (size_t)(n0 + row0 + 64) * 1024 + cbe;

    const f32x4 fz = {0.f, 0.f, 0.f, 0.f};
    f32x4 acc[4][4];
#pragma unroll
    for (int i = 0; i < 4; ++i)
#pragma unroll
        for (int j = 0; j < 4; ++j) acc[i][j] = fz;

    for (int k0 = 0; k0 < 1024; k0 += 32) {
        gload16(aldst0, asrc0 + k0);
        gload16(aldst1, asrc1 + k0);
        gload16(bldst0, bsrc0 + k0);
        gload16(bldst1, bsrc1 + k0);
        __syncthreads();
        bf16x8 af[4], bv[4];
#pragma unroll
        for (int i = 0; i < 4; ++i)
            af[i] = *(const bf16x8*)((const char*)Al + swz(wm + i * 16 + l15, lg * 16));
#pragma unroll
        for (int j = 0; j < 4; ++j)
            bv[j] = *(const bf16x8*)((const char*)Bl + swz(wn + j * 16 + l15, lg * 16));
#pragma unroll
        for (int i = 0; i < 4; ++i)
#pragma unroll
            for (int j = 0; j < 4; ++j)
                acc[i][j] = __builtin_amdgcn_mfma_f32_16x16x32_bf16(af[i], bv[j], acc[i][j], 0, 0, 0);
        __syncthreads();
    }
#pragma unroll
    for (int i = 0; i < 4; ++i)
#pragma unroll
        for (int j = 0; j < 4; ++j)
#pragma unroll
            for (int r = 0; r < 4; ++r) {
                int m = m0 + wm + i * 16 + lg * 4 + r;
                int n = n0 + wn + j * 16 + l15;
                int bb = m >> 10, s = m & 1023, h = n >> 6, d = n & 63;
                O[((size_t)(bb * 16 + h) * 1024 + s) * 64 + d] = (bf16)acc[i][j][r];
            }
}

// ---------------- Vh (B,H,S,64) -> VhT (B,H,64,S) ----------------
__global__ __launch_bounds__(512) void vh_t(const bf16* __restrict__ Vh, bf16* __restrict__ VhT)
{
    __shared__ bf16 tile[64][65];
    int bh = blockIdx.y;
    int s0 = blockIdx.x * 64;
    int tx = threadIdx.x, ty = threadIdx.y; // (64,8)
    const bf16* src = Vh + (size_t)bh * 1024 * 64;
#pragma unroll
    for (int i = 0; i < 8; ++i)
        tile[ty + i * 8][tx] = src[(size_t)(s0 + ty + i * 8) * 64 + tx];
    __syncthreads();
    bf16* dst = VhT + (size_t)bh * 64 * 1024;
#pragma unroll
    for (int i = 0; i < 8; ++i)
        dst[(size_t)(ty + i * 8) * 1024 + s0 + tx] = tile[tx][ty + i * 8];
}

// ---------------- kernel A: fused QK^T + masked exp + rowsum + PV ----------------
__global__ __launch_bounds__(512, 4) void attn_pv(
    const bf16* __restrict__ Qh, const bf16* __restrict__ Kh,
    const bf16* __restrict__ VhT, const unsigned* __restrict__ mbits,
    float* __restrict__ rowinv, bf16* __restrict__ ctx)
{
    int bh = blockIdx.x;
    int b = bh >> 4, h = bh & 15;
    int tid = threadIdx.x;
    int w = tid >> 6, l = tid & 63;
    int l15 = l & 15, lg = l >> 4;
    int q0 = blockIdx.y * 128 + w * 16;

    const bf16* Qb = Qh + (size_t)bh * 65536;
    const bf16* Kb = Kh + (size_t)bh * 65536;
    const bf16* Vt = VhT + (size_t)bh * 65536;
    const unsigned* mbrow = mbits + ((size_t)b * 1024 + q0 + l15) * 32;

    __shared__ char lds[65536];
    char* const Kl = lds;                      // [128 keys][64 d] bf16 swz, 16KB
    char* const Vl = lds + 16384;              // [64 d][128 keys] bf16 swz, 16KB
    char* const St = lds + 32768 + w * 4096;   // wave-private [16 q][128 k] bf16

    const int skr = tid >> 2;            // key row 0..127
    const int skb = (tid & 3) * 32;      // byte in 128B row
    const int sks = (skr & 7) << 4;
    const int svr = tid >> 3;            // d row 0..63
    const int svb = (tid & 7) * 32;      // byte in 256B row
    const int svs = (svr & 7) << 4;
    const int rsw = (l15 & 7) << 4;
    const int ko0 = (lg * 16) ^ rsw;
    const int ko1 = (64 + lg * 16) ^ rsw;

    bf16x8 qf0 = *(const bf16x8*)(Qb + (size_t)(q0 + l15) * 64 + lg * 8);
    bf16x8 qf1 = *(const bf16x8*)(Qb + (size_t)(q0 + l15) * 64 + 32 + lg * 8);

    const f32x4 fz = {0.f, 0.f, 0.f, 0.f};

    {   // prologue: stage chunk 0 (K and V)
        const bf16* src = Kb + (size_t)skr * 64 + (skb >> 1);
        bf16x8 a = *(const bf16x8*)src;
        bf16x8 b2 = *(const bf16x8*)(src + 8);
        const bf16* vsrc = Vt + (size_t)svr * 1024 + (svb >> 1);
        bf16x8 va = *(const bf16x8*)vsrc;
        bf16x8 vb = *(const bf16x8*)(vsrc + 8);
        *(bf16x8*)(Kl + skr * 128 + (skb ^ sks)) = a;
        *(bf16x8*)(Kl + skr * 128 + ((skb + 16) ^ sks)) = b2;
        *(bf16x8*)(Vl + svr * 256 + (svb ^ svs)) = va;
        *(bf16x8*)(Vl + svr * 256 + ((svb + 16) ^ svs)) = vb;
    }
    __syncthreads();

    f32x4 oacc[4];
#pragma unroll
    for (int d0 = 0; d0 < 4; ++d0) oacc[d0] = fz;
    float ps = 0.f;

    for (int c = 0; c < 8; ++c) {
        bf16x8 nk0, nk1, nv0, nv1;
        if (c < 7) {   // prefetch chunk c+1 into registers
            const bf16* src = Kb + (size_t)((c + 1) * 128 + skr) * 64 + (skb >> 1);
            nk0 = *(const bf16x8*)src;
            nk1 = *(const bf16x8*)(src + 8);
            const bf16* vsrc = Vt + (size_t)svr * 1024 + (c + 1) * 128 + (svb >> 1);
            nv0 = *(const bf16x8*)vsrc;
            nv1 = *(const bf16x8*)(vsrc + 8);
        }
        u32x4 mw = *(const u32x4*)(mbrow + c * 4);
        f32x4 st[8];
#pragma unroll
        for (int f = 0; f < 8; ++f) st[f] = fz;
#pragma unroll
        for (int f = 0; f < 8; ++f) {
            bf16x8 kf = *(const bf16x8*)(Kl + (f * 16 + l15) * 128 + ko0);
            st[f] = __builtin_amdgcn_mfma_f32_16x16x32_bf16(kf, qf0, st[f], 0, 0, 0);
        }
#pragma unroll
        for (int f = 0; f < 8; ++f) {
            bf16x8 kf = *(const bf16x8*)(Kl + (f * 16 + l15) * 128 + ko1);
            st[f] = __builtin_amdgcn_mfma_f32_16x16x32_bf16(kf, qf1, st[f], 0, 0, 0);
        }
        // masked exp; write P row-major into wave-private St
#pragma unroll
        for (int f = 0; f < 8; ++f) {
            unsigned wb = mw[f >> 1] >> (((f & 1) << 4) + (lg << 2));
            f32x4 o;
            o[0] = (wb & 1u)        ? __expf(st[f][0] * 0.125f) : 0.f;
            o[1] = ((wb >> 1) & 1u) ? __expf(st[f][1] * 0.125f) : 0.f;
            o[2] = ((wb >> 2) & 1u) ? __expf(st[f][2] * 0.125f) : 0.f;
            o[3] = ((wb >> 3) & 1u) ? __expf(st[f][3] * 0.125f) : 0.f;
            ps += (o[0] + o[1]) + (o[2] + o[3]);
            u32x2 pr; pr[0] = packb(o[0], o[1]); pr[1] = packb(o[2], o[3]);
            *(u32x2*)(St + l15 * 256 + ((f * 32 + lg * 8) ^ rsw)) = pr;
        }
        // PV: B-frag = contiguous read of St row q=l15
#pragma unroll
        for (int ks = 0; ks < 4; ++ks) {
            bf16x8 pf = *(const bf16x8*)(St + l15 * 256 + ((ks * 64 + lg * 16) ^ rsw));
#pragma unroll
            for (int d0 = 0; d0 < 4; ++d0) {
                bf16x8 vf = *(const bf16x8*)(Vl + (d0 * 16 + l15) * 256 + ((ks * 64 + lg * 16) ^ rsw));
                oacc[d0] = __builtin_amdgcn_mfma_f32_16x16x32_bf16(vf, pf, oacc[d0], 0, 0, 0);
            }
        }
        __syncthreads();
        if (c < 7) {
            *(bf16x8*)(Kl + skr * 128 + (skb ^ sks)) = nk0;
            *(bf16x8*)(Kl + skr * 128 + ((skb + 16) ^ sks)) = nk1;
            *(bf16x8*)(Vl + svr * 256 + (svb ^ svs)) = nv0;
            *(bf16x8*)(Vl + svr * 256 + ((svb + 16) ^ svs)) = nv1;
        }
        __syncthreads();
    }
    ps += __shfl_xor(ps, 16, 64);
    ps += __shfl_xor(ps, 32, 64);
    float inv = 1.f / ps;
    if (l < 16) rowinv[(size_t)bh * 1024 + q0 + l15] = inv;

    bf16* crow = ctx + ((size_t)(b * 1024 + q0 + l15)) * 1024 + h * 64;
#pragma unroll
    for (int d0 = 0; d0 < 4; ++d0) {
        bf16x4 cv;
#pragma unroll
        for (int r = 0; r < 4; ++r) cv[r] = (bf16)(oacc[d0][r] * inv);
        *(bf16x4*)(crow + d0 * 16 + lg * 4) = cv;
    }
}

// ---------------- kernel B: attn writer (coalesced) ----------------
__global__ __launch_bounds__(512, 4) void attn_write(
    const bf16* __restrict__ Qh, const bf16* __restrict__ Kh,
    const unsigned* __restrict__ mbits, const float* __restrict__ rowinv,
    float* __restrict__ attn_out)
{
    int bh = blockIdx.x;
    int b = bh >> 4;
    int tid = threadIdx.x;
    int w = tid >> 6, l = tid & 63;
    int l15 = l & 15, lg = l >> 4;
    int q0 = blockIdx.y * 128 + w * 16;

    const bf16* Qb = Qh + (size_t)bh * 65536;
    const bf16* Kb = Kh + (size_t)bh * 65536;

    __shared__ char lds[69632];
    char* const K0 = lds;
    char* const K1 = lds + 16384;
    char* const St = lds + 32768 + w * 4608;   // 16 rows x 288B, wave-private

    const int skr = tid >> 2;
    const int skb = (tid & 3) * 32;
    const int sks = (skr & 7) << 4;
    const int rsw = (l15 & 7) << 4;
    const int ko0 = (lg * 16) ^ rsw;
    const int ko1 = (64 + lg * 16) ^ rsw;

    bf16x8 qf0 = *(const bf16x8*)(Qb + (size_t)(q0 + l15) * 64 + lg * 8);
    bf16x8 qf1 = *(const bf16x8*)(Qb + (size_t)(q0 + l15) * 64 + 32 + lg * 8);

    const int rq = l >> 3;               // 0..7
    const int rk = (l & 7) * 4;          // 0..28
    const float iv0 = rowinv[(size_t)bh * 1024 + q0 + rq];
    const float iv1 = rowinv[(size_t)bh * 1024 + q0 + 8 + rq];
    const unsigned* mb0 = mbits + ((size_t)b * 1024 + q0 + rq) * 32;
    const unsigned* mb1 = mbits + ((size_t)b * 1024 + q0 + 8 + rq) * 32;
    float* abase = attn_out + ((size_t)bh * 1024 + q0) * 1024;

    const f32x4 fz = {0.f, 0.f, 0.f, 0.f};

    {   // stage chunk 0 K
        const bf16* src = Kb + (size_t)skr * 64 + (skb >> 1);
        bf16x8 a = *(const bf16x8*)src;
        bf16x8 bb2 = *(const bf16x8*)(src + 8);
        *(bf16x8*)(K0 + skr * 128 + (skb ^ sks)) = a;
        *(bf16x8*)(K0 + skr * 128 + ((skb + 16) ^ sks)) = bb2;
    }

    for (int c = 0; c < 8; ++c) {
        __syncthreads();
        bf16x8 nk0, nk1;
        if (c < 7) {
            const bf16* src = Kb + (size_t)((c + 1) * 128 + skr) * 64 + (skb >> 1);
            nk0 = *(const bf16x8*)src;
            nk1 = *(const bf16x8*)(src + 8);
        }
        u32x4 mw0 = *(const u32x4*)(mb0 + c * 4);
        u32x4 mw1 = *(const u32x4*)(mb1 + c * 4);
        const char* Kc = (c & 1) ? K1 : K0;
        f32x4 st[8];
#pragma unroll
        for (int f = 0; f < 8; ++f) st[f] = fz;
#pragma unroll
        for (int f = 0; f < 8; ++f) {
            bf16x8 kf = *(const bf16x8*)(Kc + (f * 16 + l15) * 128 + ko0);
            st[f] = __builtin_amdgcn_mfma_f32_16x16x32_bf16(kf, qf0, st[f], 0, 0, 0);
        }
#pragma unroll
        for (int f = 0; f < 8; ++f) {
            bf16x8 kf = *(const bf16x8*)(Kc + (f * 16 + l15) * 128 + ko1);
            st[f] = __builtin_amdgcn_mfma_f32_16x16x32_bf16(kf, qf1, st[f], 0, 0, 0);
        }
        const int qsw = (l15 & 7) << 3;
#pragma unroll
        for (int f = 0; f < 8; ++f) {
#pragma unroll
            for (int j = 0; j < 2; ++j) {
                unsigned val = packb(__expf(st[f][2 * j] * 0.125f),
                                     __expf(st[f][2 * j + 1] * 0.125f));
                int kbyte = f * 32 + lg * 8 + j * 4;
                *(unsigned*)(St + l15 * 288 + (kbyte ^ qsw)) = val;
            }
        }
#pragma unroll
        for (int ri = 0; ri < 8; ++ri) {
            int qq = rq + 8 * (ri & 1);
            int kk = rk + 32 * (ri >> 1);
            bf16x4 pv4 = *(const bf16x4*)(St + qq * 288 + ((kk * 2) ^ ((qq & 7) << 3)));
            unsigned wm = ((ri & 1) ? mw1[ri >> 1] : mw0[ri >> 1]) >> rk;
            float iv = (ri & 1) ? iv1 : iv0;
            f32x4 o;
            o[0] = (wm & 1u)        ? (float)pv4[0] * iv : 0.f;
            o[1] = ((wm >> 1) & 1u) ? (float)pv4[1] * iv : 0.f;
            o[2] = ((wm >> 2) & 1u) ? (float)pv4[2] * iv : 0.f;
            o[3] = ((wm >> 3) & 1u) ? (float)pv4[3] * iv : 0.f;
            *(f32x4*)(abase + (size_t)qq * 1024 + c * 128 + kk) = o;
        }
        if (c < 7) {
            char* kdst = ((c & 1) ? K0 : K1) + skr * 128;
            *(bf16x8*)(kdst + (skb ^ sks)) = nk0;
            *(bf16x8*)(kdst + ((skb + 16) ^ sks)) = nk1;
        }
    }
}

// ---------------- FC GEMM + residual -> preLN f32 ----------------
__global__ __launch_bounds__(256) void fc_gemm(
    const bf16* __restrict__ ctx, const bf16* __restrict__ WT,
    const float* __restrict__ resid, float* __restrict__ preLN)
{
    __shared__ bf16 Al[128 * 32];
    __shared__ bf16 Bl[128 * 32];
    int tid = threadIdx.x;
    int w = tid >> 6, l = tid & 63;
    int l15 = l & 15, lg = l >> 4;
    int m0 = blockIdx.y * 128, n0 = blockIdx.x * 128;
    int wm = (w >> 1) * 64, wn = (w & 1) * 64;

    int rr0 = tid >> 2;
    int row0 = rr0 ^ ((rr0 >> 2) & 1);
    int cbe = (((tid & 3) * 16) ^ ((row0 & 3) << 4)) >> 1;
    char* aldst0 = (char*)Al + w * 1024;
    char* aldst1 = (char*)Al + 4096 + w * 1024;
    char* bldst0 = (char*)Bl + w * 1024;
    char* bldst1 = (char*)Bl + 4096 + w * 1024;
    const bf16* asrc0 = ctx + (size_t)(m0 + row0) * 1024 + cbe;
    const bf16* asrc1 = ctx + (size_t)(m0 + row0 + 64) * 1024 + cbe;
    const bf16* bsrc0 = WT + (size_t)(n0 + row0) * 1024 + cbe;
    const bf16* bsrc1 = WT + (size_t)(n0 + row0 + 64) * 1024 + cbe;

    const f32x4 fz = {0.f, 0.f, 0.f, 0.f};
    f32x4 acc[4][4];
#pragma unroll
    for (int i = 0; i < 4; ++i)
#pragma unroll
        for (int j = 0; j < 4; ++j) acc[i][j] = fz;

    for (int k0 = 0; k0 < 1024; k0 += 32) {
        gload16(aldst0, asrc0 + k0);
        gload16(aldst1, asrc1 + k0);
        gload16(bldst0, bsrc0 + k0);
        gload16(bldst1, bsrc1 + k0);
        __syncthreads();
        bf16x8 af[4], bv[4];
#pragma unroll
        for (int i = 0; i < 4; ++i)
            af[i] = *(const bf16x8*)((const char*)Al + swz(wm + i * 16 + l15, lg * 16));
#pragma unroll
        for (int j = 0; j < 4; ++j)
            bv[j] = *(const bf16x8*)((const char*)Bl + swz(wn + j * 16 + l15, lg * 16));
#pragma unroll
        for (int i = 0; i < 4; ++i)
#pragma unroll
            for (int j = 0; j < 4; ++j)
                acc[i][j] = __builtin_amdgcn_mfma_f32_16x16x32_bf16(af[i], bv[j], acc[i][j], 0, 0, 0);
        __syncthreads();
    }
#pragma unroll
    for (int i = 0; i < 4; ++i)
#pragma unroll
        for (int j = 0; j < 4; ++j)
#pragma unroll
            for (int r = 0; r < 4; ++r) {
                int m = m0 + wm + i * 16 + lg * 4 + r;
                int n = n0 + wn + j * 16 + l15;
                preLN[(size_t)m * 1024 + n] = acc[i][j][r] + resid[(size_t)m * 1024 + n];
            }
}

// ---------------- LayerNorm ----------------
__global__ __launch_bounds__(256) void ln_kernel(
    const float* __restrict__ x, const float* __restrict__ gamma,
    const float* __restrict__ beta, float* __restrict__ out)
{
    int row = blockIdx.x, t = threadIdx.x;
    const float* xr = x + (size_t)row * 1024;
    f32x4 v = *(const f32x4*)(xr + t * 4);
    float s = v[0] + v[1] + v[2] + v[3];
    float s2 = v[0] * v[0] + v[1] * v[1] + v[2] * v[2] + v[3] * v[3];
#pragma unroll
    for (int m = 1; m < 64; m <<= 1) {
        s += __shfl_xor(s, m, 64);
        s2 += __shfl_xor(s2, m, 64);
    }
    __shared__ float rs[4], rs2[4];
    if ((t & 63) == 0) { rs[t >> 6] = s; rs2[t >> 6] = s2; }
    __syncthreads();
    float S = rs[0] + rs[1] + rs[2] + rs[3];
    float S2 = rs2[0] + rs2[1] + rs2[2] + rs2[3];
    float mu = S * (1.f / 1024.f);
    float var = S2 * (1.f / 1024.f) - mu * mu;
    float rinv = rsqrtf(var + 1e-6f);
    f32x4 g = *(const f32x4*)(gamma + t * 4);
    f32x4 bb = *(const f32x4*)(beta + t * 4);
    f32x4 o;
#pragma unroll
    for (int j = 0; j < 4; ++j) o[j] = (v[j] - mu) * rinv * g[j] + bb[j];
    *(f32x4*)(out + (size_t)row * 1024 + t * 4) = o;
}

extern "C" void kernel_launch(void* const* d_in, const int* in_sizes, int n_in,
                              void* d_out, int out_size, void* d_ws, size_t ws_size,
                              hipStream_t stream) {
    const float* q     = (const float*)d_in[0];
    const float* k     = (const float*)d_in[1];
    const float* v     = (const float*)d_in[2];
    const int*   mask  = (const int*)d_in[3];
    const float* w_qs  = (const float*)d_in[4];
    const float* w_ks  = (const float*)d_in[5];
    const float* w_vs  = (const float*)d_in[6];
    const float* w_fc  = (const float*)d_in[7];
    const float* gamma = (const float*)d_in[8];
    const float* beta  = (const float*)d_in[9];

    float* out  = (float*)d_out;
    float* attn = out + (size_t)4 * 1024 * 1024; // second tuple output

    char* ws = (char*)d_ws;
    bf16* wqT   = (bf16*)(ws + (0ull  << 20));
    bf16* wkT   = (bf16*)(ws + (2ull  << 20));
    bf16* wvT   = (bf16*)(ws + (4ull  << 20));
    bf16* wfcT  = (bf16*)(ws + (6ull  << 20));
    bf16* Qh    = (bf16*)(ws + (8ull  << 20));
    bf16* Kh    = (bf16*)(ws + (16ull << 20));
    bf16* Vh    = (bf16*)(ws + (24ull << 20));
    bf16* VhT   = (bf16*)(ws + (32ull << 20));
    bf16* ctx   = (bf16*)(ws + (40ull << 20));
    float* preLN = (float*)(ws + (48ull << 20));
    float* rowinv = (float*)(ws + (24ull << 20));
    unsigned long long* mbits = (unsigned long long*)(ws + (25ull << 20)); // 512KB

    // bf16 copies of q/k/v live in the attn output region (dead until attn_write,
    // which runs after all proj reads; attn_write then overwrites every byte).
    char* scratch = (char*)attn;
    bf16* qb = (bf16*)scratch;
    bf16* kb = qb + (size_t)4 * 1024 * 1024;
    bf16* vb = kb + (size_t)4 * 1024 * 1024;

    cvt_bf16<<<dim3(2048, 1, 3), 256, 0, stream>>>(q, k, v, qb, kb, vb);
    wt_cvt<<<dim3(32, 32, 4), dim3(32, 8), 0, stream>>>(w_qs, w_ks, w_vs, w_fc,
                                                        wqT, wkT, wvT, wfcT);
    proj_gemm<<<dim3(8, 32, 3), 256, 0, stream>>>(qb, kb, vb, wqT, wkT, wvT, Qh, Kh, Vh);
    vh_t<<<dim3(16, 64), dim3(64, 8), 0, stream>>>(Vh, VhT);
    mask_pack<<<256, 256, 0, stream>>>(mask, mbits);
    attn_pv<<<dim3(64, 8), 512, 0, stream>>>(Qh, Kh, VhT, (const unsigned*)mbits,
                                             rowinv, ctx);
    attn_write<<<dim3(64, 8), 512, 0, stream>>>(Qh, Kh, (const unsigned*)mbits,
                                                rowinv, attn);
    fc_gemm<<<dim3(8, 32), 256, 0, stream>>>(ctx, wfcT, q, preLN);
    ln_kernel<<<4096, 256, 0, stream>>>(preLN, gamma, beta, out);
}

// Round 9
// 234.828 us; speedup vs baseline: 1.0917x; 1.0036x over previous
//
#include <hip/hip_runtime.h>
#include <stdint.h>

typedef __bf16 bf16;
typedef __bf16 bf16x2 __attribute__((ext_vector_type(2)));
typedef __bf16 bf16x4 __attribute__((ext_vector_type(4)));
typedef __bf16 bf16x8 __attribute__((ext_vector_type(8)));
typedef float f32x4 __attribute__((ext_vector_type(4)));
typedef int i32x4 __attribute__((ext_vector_type(4)));
typedef unsigned u32x2 __attribute__((ext_vector_type(2)));
typedef unsigned u32x4 __attribute__((ext_vector_type(4)));

// XOR swizzle for [rows][32] bf16 LDS tiles (64B row stride).
__device__ __forceinline__ int swz(int row, int colb) {
    return (row * 64 + colb) ^ ((row & 7) << 4);
}

__device__ __forceinline__ unsigned packb(float a, float b) {
    bf16x2 t; t[0] = (bf16)a; t[1] = (bf16)b;
    return __builtin_bit_cast(unsigned, t);
}

// async global->LDS 16B copy (dest = wave-uniform base + lane*16)
__device__ __forceinline__ void gload16(void* lds, const void* g) {
    __builtin_amdgcn_global_load_lds(
        (const __attribute__((address_space(1))) void*)g,
        (__attribute__((address_space(3))) void*)lds, 16, 0, 0);
}

// ---------------- q/k/v f32 -> bf16 ----------------
__global__ __launch_bounds__(256) void cvt_bf16(
    const float* __restrict__ q, const float* __restrict__ k, const float* __restrict__ v,
    bf16* __restrict__ oq, bf16* __restrict__ ok, bf16* __restrict__ ov)
{
    int z = blockIdx.z;
    const float* src = z == 0 ? q : z == 1 ? k : v;
    bf16* dst = z == 0 ? oq : z == 1 ? ok : ov;
    size_t i = ((size_t)blockIdx.x * 256 + threadIdx.x) * 8;
    f32x4 a = *(const f32x4*)(src + i);
    f32x4 b = *(const f32x4*)(src + i + 4);
    bf16x8 o;
#pragma unroll
    for (int j = 0; j < 4; ++j) { o[j] = (bf16)a[j]; o[4 + j] = (bf16)b[j]; }
    *(bf16x8*)(dst + i) = o;
}

// ---------------- mask -> bitmask (u32 per 32 keys) ----------------
__global__ __launch_bounds__(256) void mask_pack(
    const int* __restrict__ mask, unsigned long long* __restrict__ mbits)
{
    int lane = threadIdx.x & 63;
    int wid = (blockIdx.x * 256 + threadIdx.x) >> 6;
    int nw = (gridDim.x * 256) >> 6;
    const int niter = (4 * 1024 * 1024) / 64;
    for (int i = wid; i < niter; i += nw) {
        int v = mask[(size_t)i * 64 + lane];
        unsigned long long bb = __ballot(v != 0);
        if (lane == 0) mbits[i] = bb;
    }
}

// ---------------- weight transpose + f32->bf16 ----------------
__global__ __launch_bounds__(256) void wt_cvt(
    const float* __restrict__ w0, const float* __restrict__ w1,
    const float* __restrict__ w2, const float* __restrict__ w3,
    bf16* __restrict__ o0, bf16* __restrict__ o1,
    bf16* __restrict__ o2, bf16* __restrict__ o3)
{
    int z = blockIdx.z;
    const float* W = z == 0 ? w0 : z == 1 ? w1 : z == 2 ? w2 : w3;
    bf16* O = z == 0 ? o0 : z == 1 ? o1 : z == 2 ? o2 : o3;
    __shared__ float tile[32][33];
    int c0 = blockIdx.x * 32, r0 = blockIdx.y * 32;
    int tx = threadIdx.x, ty = threadIdx.y; // (32,8)
#pragma unroll
    for (int i = 0; i < 4; ++i)
        tile[ty + i * 8][tx] = W[(size_t)(r0 + ty + i * 8) * 1024 + c0 + tx];
    __syncthreads();
#pragma unroll
    for (int i = 0; i < 4; ++i)
        O[(size_t)(c0 + ty + i * 8) * 1024 + r0 + tx] = (bf16)tile[tx][ty + i * 8];
}

// ---------------- projection GEMM -> head-major bf16 (gload_lds staging) ------
__global__ __launch_bounds__(256) void proj_gemm(
    const bf16* __restrict__ Aq, const bf16* __restrict__ Ak, const bf16* __restrict__ Av,
    const bf16* __restrict__ Wq, const bf16* __restrict__ Wk, const bf16* __restrict__ Wv,
    bf16* __restrict__ Oq, bf16* __restrict__ Ok, bf16* __restrict__ Ov)
{
    int z = blockIdx.z;
    const bf16* A = z == 0 ? Aq : z == 1 ? Ak : Av;
    const bf16* WT = z == 0 ? Wq : z == 1 ? Wk : Wv;
    bf16* O = z == 0 ? Oq : z == 1 ? Ok : Ov;

    __shared__ bf16 Al[128 * 32];
    __shared__ bf16 Bl[128 * 32];

    int tid = threadIdx.x;
    int w = tid >> 6, l = tid & 63;
    int l15 = l & 15, lg = l >> 4;
    int m0 = blockIdx.y * 128, n0 = blockIdx.x * 128;
    int wm = (w >> 1) * 64, wn = (w & 1) * 64;

    int rr0 = tid >> 2;
    int row0 = rr0 ^ ((rr0 >> 2) & 1);
    int cbe = (((tid & 3) * 16) ^ ((row0 & 3) << 4)) >> 1;
    char* aldst0 = (char*)Al + w * 1024;
    char* aldst1 = (char*)Al + 4096 + w * 1024;
    char* bldst0 = (char*)Bl + w * 1024;
    char* bldst1 = (char*)Bl + 4096 + w * 1024;
    const bf16* asrc0 = A + (size_t)(m0 + row0) * 1024 + cbe;
    const bf16* asrc1 = A + (size_t)(m0 + row0 + 64) * 1024 + cbe;
    const bf16* bsrc0 = WT + (size_t)(n0 + row0) * 1024 + cbe;
    const bf16* bsrc1 = WT + (size_t)(n0 + row0 + 64) * 1024 + cbe;

    const f32x4 fz = {0.f, 0.f, 0.f, 0.f};
    f32x4 acc[4][4];
#pragma unroll
    for (int i = 0; i < 4; ++i)
#pragma unroll
        for (int j = 0; j < 4; ++j) acc[i][j] = fz;

    for (int k0 = 0; k0 < 1024; k0 += 32) {
        gload16(aldst0, asrc0 + k0);
        gload16(aldst1, asrc1 + k0);
        gload16(bldst0, bsrc0 + k0);
        gload16(bldst1, bsrc1 + k0);
        __syncthreads();
        bf16x8 af[4], bv[4];
#pragma unroll
        for (int i = 0; i < 4; ++i)
            af[i] = *(const bf16x8*)((const char*)Al + swz(wm + i * 16 + l15, lg * 16));
#pragma unroll
        for (int j = 0; j < 4; ++j)
            bv[j] = *(const bf16x8*)((const char*)Bl + swz(wn + j * 16 + l15, lg * 16));
#pragma unroll
        for (int i = 0; i < 4; ++i)
#pragma unroll
            for (int j = 0; j < 4; ++j)
                acc[i][j] = __builtin_amdgcn_mfma_f32_16x16x32_bf16(af[i], bv[j], acc[i][j], 0, 0, 0);
        __syncthreads();
    }
#pragma unroll
    for (int i = 0; i < 4; ++i)
#pragma unroll
        for (int j = 0; j < 4; ++j)
#pragma unroll
            for (int r = 0; r < 4; ++r) {
                int m = m0 + wm + i * 16 + lg * 4 + r;
                int n = n0 + wn + j * 16 + l15;
                int bb = m >> 10, s = m & 1023, h = n >> 6, d = n & 63;
                O[((size_t)(bb * 16 + h) * 1024 + s) * 64 + d] = (bf16)acc[i][j][r];
            }
}

// ---------------- Vh (B,H,S,64) -> VhT (B,H,64,S) ----------------
__global__ __launch_bounds__(512) void vh_t(const bf16* __restrict__ Vh, bf16* __restrict__ VhT)
{
    __shared__ bf16 tile[64][65];
    int bh = blockIdx.y;
    int s0 = blockIdx.x * 64;
    int tx = threadIdx.x, ty = threadIdx.y; // (64,8)
    const bf16* src = Vh + (size_t)bh * 1024 * 64;
#pragma unroll
    for (int i = 0; i < 8; ++i)
        tile[ty + i * 8][tx] = src[(size_t)(s0 + ty + i * 8) * 64 + tx];
    __syncthreads();
    bf16* dst = VhT + (size_t)bh * 64 * 1024;
#pragma unroll
    for (int i = 0; i < 8; ++i)
        dst[(size_t)(ty + i * 8) * 1024 + s0 + tx] = tile[tx][ty + i * 8];
}

// ---------------- kernel A: fused QK^T + masked exp + rowsum + PV ----------------
// 4-wave blocks, KVBLK=64, 24KB LDS -> 4+ blocks/CU: barriers lockstep only 4
// waves; independent blocks on the CU cover each other's staging latency.
__global__ __launch_bounds__(256, 4) void attn_pv(
    const bf16* __restrict__ Qh, const bf16* __restrict__ Kh,
    const bf16* __restrict__ VhT, const unsigned* __restrict__ mbits,
    float* __restrict__ rowinv, bf16* __restrict__ ctx)
{
    int bh = blockIdx.x;
    int b = bh >> 4, h = bh & 15;
    int tid = threadIdx.x;
    int w = tid >> 6, l = tid & 63;
    int l15 = l & 15, lg = l >> 4;
    int q0 = blockIdx.y * 64 + w * 16;

    const bf16* Qb = Qh + (size_t)bh * 65536;
    const bf16* Kb = Kh + (size_t)bh * 65536;
    const bf16* Vt = VhT + (size_t)bh * 65536;
    const unsigned* mbrow = mbits + ((size_t)b * 1024 + q0 + l15) * 32;

    __shared__ char lds[24576];
    char* const Kl = lds;                      // [64 keys][128B d] swz, 8KB
    char* const Vl = lds + 8192;               // [64 d][128B keys] swz, 8KB
    char* const St = lds + 16384 + w * 2048;   // wave-private [16 q][128B keys]

    const int skr = tid >> 2;            // row 0..63 (key for K, d for V)
    const int skb = (tid & 3) * 32;      // byte in 128B row
    const int sks = (skr & 7) << 4;
    const int rsw = (l15 & 7) << 4;
    const int ko0 = (lg * 16) ^ rsw;
    const int ko1 = (64 + lg * 16) ^ rsw;

    bf16x8 qf0 = *(const bf16x8*)(Qb + (size_t)(q0 + l15) * 64 + lg * 8);
    bf16x8 qf1 = *(const bf16x8*)(Qb + (size_t)(q0 + l15) * 64 + 32 + lg * 8);

    const f32x4 fz = {0.f, 0.f, 0.f, 0.f};

    {   // prologue: stage chunk 0 (K and V)
        const bf16* src = Kb + (size_t)skr * 64 + (skb >> 1);
        bf16x8 a = *(const bf16x8*)src;
        bf16x8 b2 = *(const bf16x8*)(src + 8);
        const bf16* vsrc = Vt + (size_t)skr * 1024 + (skb >> 1);
        bf16x8 va = *(const bf16x8*)vsrc;
        bf16x8 vb = *(const bf16x8*)(vsrc + 8);
        *(bf16x8*)(Kl + skr * 128 + (skb ^ sks)) = a;
        *(bf16x8*)(Kl + skr * 128 + ((skb + 16) ^ sks)) = b2;
        *(bf16x8*)(Vl + skr * 128 + (skb ^ sks)) = va;
        *(bf16x8*)(Vl + skr * 128 + ((skb + 16) ^ sks)) = vb;
    }
    __syncthreads();

    f32x4 oacc[4];
#pragma unroll
    for (int d0 = 0; d0 < 4; ++d0) oacc[d0] = fz;
    float ps = 0.f;

    for (int c = 0; c < 16; ++c) {
        bf16x8 nk0, nk1, nv0, nv1;
        if (c < 15) {   // prefetch chunk c+1 into registers
            const bf16* src = Kb + (size_t)((c + 1) * 64 + skr) * 64 + (skb >> 1);
            nk0 = *(const bf16x8*)src;
            nk1 = *(const bf16x8*)(src + 8);
            const bf16* vsrc = Vt + (size_t)skr * 1024 + (c + 1) * 64 + (skb >> 1);
            nv0 = *(const bf16x8*)vsrc;
            nv1 = *(const bf16x8*)(vsrc + 8);
        }
        u32x2 mw = *(const u32x2*)(mbrow + c * 2);
        f32x4 st[4];
#pragma unroll
        for (int f = 0; f < 4; ++f) st[f] = fz;
#pragma unroll
        for (int f = 0; f < 4; ++f) {
            bf16x8 kf = *(const bf16x8*)(Kl + (f * 16 + l15) * 128 + ko0);
            st[f] = __builtin_amdgcn_mfma_f32_16x16x32_bf16(kf, qf0, st[f], 0, 0, 0);
        }
#pragma unroll
        for (int f = 0; f < 4; ++f) {
            bf16x8 kf = *(const bf16x8*)(Kl + (f * 16 + l15) * 128 + ko1);
            st[f] = __builtin_amdgcn_mfma_f32_16x16x32_bf16(kf, qf1, st[f], 0, 0, 0);
        }
        // masked exp; write P row-major into wave-private St
#pragma unroll
        for (int f = 0; f < 4; ++f) {
            unsigned wb = mw[f >> 1] >> (((f & 1) << 4) + (lg << 2));
            f32x4 o;
            o[0] = (wb & 1u)        ? __expf(st[f][0] * 0.125f) : 0.f;
            o[1] = ((wb >> 1) & 1u) ? __expf(st[f][1] * 0.125f) : 0.f;
            o[2] = ((wb >> 2) & 1u) ? __expf(st[f][2] * 0.125f) : 0.f;
            o[3] = ((wb >> 3) & 1u) ? __expf(st[f][3] * 0.125f) : 0.f;
            ps += (o[0] + o[1]) + (o[2] + o[3]);
            u32x2 pr; pr[0] = packb(o[0], o[1]); pr[1] = packb(o[2], o[3]);
            *(u32x2*)(St + l15 * 128 + ((f * 32 + lg * 8) ^ rsw)) = pr;
        }
        // PV: B-frag = contiguous read of St row q=l15
#pragma unroll
        for (int ks = 0; ks < 2; ++ks) {
            bf16x8 pf = *(const bf16x8*)(St + l15 * 128 + ((ks * 64 + lg * 16) ^ rsw));
#pragma unroll
            for (int d0 = 0; d0 < 4; ++d0) {
                bf16x8 vf = *(const bf16x8*)(Vl + (d0 * 16 + l15) * 128 + ((ks * 64 + lg * 16) ^ rsw));
                oacc[d0] = __builtin_amdgcn_mfma_f32_16x16x32_bf16(vf, pf, oacc[d0], 0, 0, 0);
            }
        }
        __syncthreads();
        if (c < 15) {
            *(bf16x8*)(Kl + skr * 128 + (skb ^ sks)) = nk0;
            *(bf16x8*)(Kl + skr * 128 + ((skb + 16) ^ sks)) = nk1;
            *(bf16x8*)(Vl + skr * 128 + (skb ^ sks)) = nv0;
            *(bf16x8*)(Vl + skr * 128 + ((skb + 16) ^ sks)) = nv1;
        }
        __syncthreads();
    }
    ps += __shfl_xor(ps, 16, 64);
    ps += __shfl_xor(ps, 32, 64);
    float inv = 1.f / ps;
    if (l < 16) rowinv[(size_t)bh * 1024 + q0 + l15] = inv;

    bf16* crow = ctx + ((size_t)(b * 1024 + q0 + l15)) * 1024 + h * 64;
#pragma unroll
    for (int d0 = 0; d0 < 4; ++d0) {
        bf16x4 cv;
#pragma unroll
        for (int r = 0; r < 4; ++r) cv[r] = (bf16)(oacc[d0][r] * inv);
        *(bf16x4*)(crow + d0 * 16 + lg * 4) = cv;
    }
}

// ---------------- kernel B: attn writer (coalesced) ----------------
// 4-wave blocks, KVBLK=64, double-buffered K, ~26KB LDS -> 4+ blocks/CU.
__global__ __launch_bounds__(256, 4) void attn_write(
    const bf16* __restrict__ Qh, const bf16* __restrict__ Kh,
    const unsigned* __restrict__ mbits, const float* __restrict__ rowinv,
    float* __restrict__ attn_out)
{
    int bh = blockIdx.x;
    int b = bh >> 4;
    int tid = threadIdx.x;
    int w = tid >> 6, l = tid & 63;
    int l15 = l & 15, lg = l >> 4;
    int q0 = blockIdx.y * 64 + w * 16;

    const bf16* Qb = Qh + (size_t)bh * 65536;
    const bf16* Kb = Kh + (size_t)bh * 65536;

    __shared__ char lds[26624];
    char* const K0 = lds;                      // 8KB each
    char* const K1 = lds + 8192;
    char* const St = lds + 16384 + w * 2560;   // 16 rows x 160B, wave-private

    const int skr = tid >> 2;
    const int skb = (tid & 3) * 32;
    const int sks = (skr & 7) << 4;
    const int rsw = (l15 & 7) << 4;
    const int ko0 = (lg * 16) ^ rsw;
    const int ko1 = (64 + lg * 16) ^ rsw;

    bf16x8 qf0 = *(const bf16x8*)(Qb + (size_t)(q0 + l15) * 64 + lg * 8);
    bf16x8 qf1 = *(const bf16x8*)(Qb + (size_t)(q0 + l15) * 64 + 32 + lg * 8);

    const int rq = l >> 3;               // 0..7
    const int rk = (l & 7) * 4;          // 0..28
    const float iv0 = rowinv[(size_t)bh * 1024 + q0 + rq];
    const float iv1 = rowinv[(size_t)bh * 1024 + q0 + 8 + rq];
    const unsigned* mb0 = mbits + ((size_t)b * 1024 + q0 + rq) * 32;
    const unsigned* mb1 = mbits + ((size_t)b * 1024 + q0 + 8 + rq) * 32;
    float* abase = attn_out + ((size_t)bh * 1024 + q0) * 1024;

    const f32x4 fz = {0.f, 0.f, 0.f, 0.f};

    {   // stage chunk 0 K
        const bf16* src = Kb + (size_t)skr * 64 + (skb >> 1);
        bf16x8 a = *(const bf16x8*)src;
        bf16x8 bb2 = *(const bf16x8*)(src + 8);
        *(bf16x8*)(K0 + skr * 128 + (skb ^ sks)) = a;
        *(bf16x8*)(K0 + skr * 128 + ((skb + 16) ^ sks)) = bb2;
    }

    for (int c = 0; c < 16; ++c) {
        __syncthreads();
        bf16x8 nk0, nk1;
        if (c < 15) {
            const bf16* src = Kb + (size_t)((c + 1) * 64 + skr) * 64 + (skb >> 1);
            nk0 = *(const bf16x8*)src;
            nk1 = *(const bf16x8*)(src + 8);
        }
        u32x2 mw0 = *(const u32x2*)(mb0 + c * 2);
        u32x2 mw1 = *(const u32x2*)(mb1 + c * 2);
        const char* Kc = (c & 1) ? K1 : K0;
        f32x4 st[4];
#pragma unroll
        for (int f = 0; f < 4; ++f) st[f] = fz;
#pragma unroll
        for (int f = 0; f < 4; ++f) {
            bf16x8 kf = *(const bf16x8*)(Kc + (f * 16 + l15) * 128 + ko0);
            st[f] = __builtin_amdgcn_mfma_f32_16x16x32_bf16(kf, qf0, st[f], 0, 0, 0);
        }
#pragma unroll
        for (int f = 0; f < 4; ++f) {
            bf16x8 kf = *(const bf16x8*)(Kc + (f * 16 + l15) * 128 + ko1);
            st[f] = __builtin_amdgcn_mfma_f32_16x16x32_bf16(kf, qf1, st[f], 0, 0, 0);
        }
        const int qsw = (l15 & 7) << 3;
#pragma unroll
        for (int f = 0; f < 4; ++f) {
#pragma unroll
            for (int j = 0; j < 2; ++j) {
                unsigned val = packb(__expf(st[f][2 * j] * 0.125f),
                                     __expf(st[f][2 * j + 1] * 0.125f));
                int kbyte = f * 32 + lg * 8 + j * 4;
                *(unsigned*)(St + l15 * 160 + (kbyte ^ qsw)) = val;
            }
        }
#pragma unroll
        for (int ri = 0; ri < 4; ++ri) {
            int qq = rq + 8 * (ri & 1);
            int kk = rk + 32 * (ri >> 1);
            bf16x4 pv4 = *(const bf16x4*)(St + qq * 160 + ((kk * 2) ^ ((qq & 7) << 3)));
            unsigned wm = ((ri & 1) ? mw1[ri >> 1] : mw0[ri >> 1]) >> rk;
            float iv = (ri & 1) ? iv1 : iv0;
            f32x4 o;
            o[0] = (wm & 1u)        ? (float)pv4[0] * iv : 0.f;
            o[1] = ((wm >> 1) & 1u) ? (float)pv4[1] * iv : 0.f;
            o[2] = ((wm >> 2) & 1u) ? (float)pv4[2] * iv : 0.f;
            o[3] = ((wm >> 3) & 1u) ? (float)pv4[3] * iv : 0.f;
            *(f32x4*)(abase + (size_t)qq * 1024 + c * 64 + kk) = o;
        }
        if (c < 15) {
            char* kdst = ((c & 1) ? K0 : K1) + skr * 128;
            *(bf16x8*)(kdst + (skb ^ sks)) = nk0;
            *(bf16x8*)(kdst + ((skb + 16) ^ sks)) = nk1;
        }
    }
}

// ---------------- FC GEMM + residual -> preLN f32 ----------------
__global__ __launch_bounds__(256) void fc_gemm(
    const bf16* __restrict__ ctx, const bf16* __restrict__ WT,
    const float* __restrict__ resid, float* __restrict__ preLN)
{
    __shared__ bf16 Al[128 * 32];
    __shared__ bf16 Bl[128 * 32];
    int tid = threadIdx.x;
    int w = tid >> 6, l = tid & 63;
    int l15 = l & 15, lg = l >> 4;
    int m0 = blockIdx.y * 128, n0 = blockIdx.x * 128;
    int wm = (w >> 1) * 64, wn = (w & 1) * 64;

    int rr0 = tid >> 2;
    int row0 = rr0 ^ ((rr0 >> 2) & 1);
    int cbe = (((tid & 3) * 16) ^ ((row0 & 3) << 4)) >> 1;
    char* aldst0 = (char*)Al + w * 1024;
    char* aldst1 = (char*)Al + 4096 + w * 1024;
    char* bldst0 = (char*)Bl + w * 1024;
    char* bldst1 = (char*)Bl + 4096 + w * 1024;
    const bf16* asrc0 = ctx + (size_t)(m0 + row0) * 1024 + cbe;
    const bf16* asrc1 = ctx + (size_t)(m0 + row0 + 64) * 1024 + cbe;
    const bf16* bsrc0 = WT + (size_t)(n0 + row0) * 1024 + cbe;
    const bf16* bsrc1 = WT + (size_t)(n0 + row0 + 64) * 1024 + cbe;

    const f32x4 fz = {0.f, 0.f, 0.f, 0.f};
    f32x4 acc[4][4];
#pragma unroll
    for (int i = 0; i < 4; ++i)
#pragma unroll
        for (int j = 0; j < 4; ++j) acc[i][j] = fz;

    for (int k0 = 0; k0 < 1024; k0 += 32) {
        gload16(aldst0, asrc0 + k0);
        gload16(aldst1, asrc1 + k0);
        gload16(bldst0, bsrc0 + k0);
        gload16(bldst1, bsrc1 + k0);
        __syncthreads();
        bf16x8 af[4], bv[4];
#pragma unroll
        for (int i = 0; i < 4; ++i)
            af[i] = *(const bf16x8*)((const char*)Al + swz(wm + i * 16 + l15, lg * 16));
#pragma unroll
        for (int j = 0; j < 4; ++j)
            bv[j] = *(const bf16x8*)((const char*)Bl + swz(wn + j * 16 + l15, lg * 16));
#pragma unroll
        for (int i = 0; i < 4; ++i)
#pragma unroll
            for (int j = 0; j < 4; ++j)
                acc[i][j] = __builtin_amdgcn_mfma_f32_16x16x32_bf16(af[i], bv[j], acc[i][j], 0, 0, 0);
        __syncthreads();
    }
#pragma unroll
    for (int i = 0; i < 4; ++i)
#pragma unroll
        for (int j = 0; j < 4; ++j)
#pragma unroll
            for (int r = 0; r < 4; ++r) {
                int m = m0 + wm + i * 16 + lg * 4 + r;
                int n = n0 + wn + j * 16 + l15;
                preLN[(size_t)m * 1024 + n] = acc[i][j][r] + resid[(size_t)m * 1024 + n];
            }
}

// ---------------- LayerNorm ----------------
__global__ __launch_bounds__(256) void ln_kernel(
    const float* __restrict__ x, const float* __restrict__ gamma,
    const float* __restrict__ beta, float* __restrict__ out)
{
    int row = blockIdx.x, t = threadIdx.x;
    const float* xr = x + (size_t)row * 1024;
    f32x4 v = *(const f32x4*)(xr + t * 4);
    float s = v[0] + v[1] + v[2] + v[3];
    float s2 = v[0] * v[0] + v[1] * v[1] + v[2] * v[2] + v[3] * v[3];
#pragma unroll
    for (int m = 1; m < 64; m <<= 1) {
        s += __shfl_xor(s, m, 64);
        s2 += __shfl_xor(s2, m, 64);
    }
    __shared__ float rs[4], rs2[4];
    if ((t & 63) == 0) { rs[t >> 6] = s; rs2[t >> 6] = s2; }
    __syncthreads();
    float S = rs[0] + rs[1] + rs[2] + rs[3];
    float S2 = rs2[0] + rs2[1] + rs2[2] + rs2[3];
    float mu = S * (1.f / 1024.f);
    float var = S2 * (1.f / 1024.f) - mu * mu;
    float rinv = rsqrtf(var + 1e-6f);
    f32x4 g = *(const f32x4*)(gamma + t * 4);
    f32x4 bb = *(const f32x4*)(beta + t * 4);
    f32x4 o;
#pragma unroll
    for (int j = 0; j < 4; ++j) o[j] = (v[j] - mu) * rinv * g[j] + bb[j];
    *(f32x4*)(out + (size_t)row * 1024 + t * 4) = o;
}

extern "C" void kernel_launch(void* const* d_in, const int* in_sizes, int n_in,
                              void* d_out, int out_size, void* d_ws, size_t ws_size,
                              hipStream_t stream) {
    const float* q     = (const float*)d_in[0];
    const float* k     = (const float*)d_in[1];
    const float* v     = (const float*)d_in[2];
    const int*   mask  = (const int*)d_in[3];
    const float* w_qs  = (const float*)d_in[4];
    const float* w_ks  = (const float*)d_in[5];
    const float* w_vs  = (const float*)d_in[6];
    const float* w_fc  = (const float*)d_in[7];
    const float* gamma = (const float*)d_in[8];
    const float* beta  = (const float*)d_in[9];

    float* out  = (float*)d_out;
    float* attn = out + (size_t)4 * 1024 * 1024; // second tuple output

    char* ws = (char*)d_ws;
    bf16* wqT   = (bf16*)(ws + (0ull  << 20));
    bf16* wkT   = (bf16*)(ws + (2ull  << 20));
    bf16* wvT   = (bf16*)(ws + (4ull  << 20));
    bf16* wfcT  = (bf16*)(ws + (6ull  << 20));
    bf16* Qh    = (bf16*)(ws + (8ull  << 20));
    bf16* Kh    = (bf16*)(ws + (16ull << 20));
    bf16* Vh    = (bf16*)(ws + (24ull << 20));
    bf16* VhT   = (bf16*)(ws + (32ull << 20));
    bf16* ctx   = (bf16*)(ws + (40ull << 20));
    float* preLN = (float*)(ws + (48ull << 20));
    float* rowinv = (float*)(ws + (24ull << 20));
    unsigned long long* mbits = (unsigned long long*)(ws + (25ull << 20)); // 512KB

    // bf16 copies of q/k/v live in the attn output region (dead until attn_write).
    char* scratch = (char*)attn;
    bf16* qb = (bf16*)scratch;
    bf16* kb = qb + (size_t)4 * 1024 * 1024;
    bf16* vb = kb + (size_t)4 * 1024 * 1024;

    cvt_bf16<<<dim3(2048, 1, 3), 256, 0, stream>>>(q, k, v, qb, kb, vb);
    wt_cvt<<<dim3(32, 32, 4), dim3(32, 8), 0, stream>>>(w_qs, w_ks, w_vs, w_fc,
                                                        wqT, wkT, wvT, wfcT);
    proj_gemm<<<dim3(8, 32, 3), 256, 0, stream>>>(qb, kb, vb, wqT, wkT, wvT, Qh, Kh, Vh);
    vh_t<<<dim3(16, 64), dim3(64, 8), 0, stream>>>(Vh, VhT);
    mask_pack<<<256, 256, 0, stream>>>(mask, mbits);
    attn_pv<<<dim3(64, 16), 256, 0, stream>>>(Qh, Kh, VhT, (const unsigned*)mbits,
                                              rowinv, ctx);
    attn_write<<<dim3(64, 16), 256, 0, stream>>>(Qh, Kh, (const unsigned*)mbits,
                                                 rowinv, attn);
    fc_gemm<<<dim3(8, 32), 256, 0, stream>>>(ctx, wfcT, q, preLN);
    ln_kernel<<<4096, 256, 0, stream>>>(preLN, gamma, beta, out);
}